// Round 5
// baseline (190.249 us; speedup 1.0000x reference)
//
#include <hip/hip_runtime.h>

#define N_NODES 2000
#define NP      2048    // Sp n-dim padding
#define KB      63      // real k-blocks (k = 2000 padded to 2016 in-block)
#define KB3     66      // padded k-blocks: slabs 63..65 of Sp zero-filled (A=0)
#define BATCH   32
#define DIM     64      // DIM_IN == DIM_OUT
#define EMB     16
#define KI      192     // CHEB_K * DIM_IN
#define WCOLS   12288   // DIM_OUT * KI

typedef __bf16 bf16;
typedef __attribute__((ext_vector_type(8))) __bf16 bf16x8;
typedef __attribute__((ext_vector_type(4))) float  f32x4;

struct alignas(8) bf16x4pk { bf16 v[4]; };

// Async global->LDS DMA, 16 B per lane (lane-contiguous within each wave).
__device__ __forceinline__ void gl_lds16(const bf16* g, bf16* l) {
    __builtin_amdgcn_global_load_lds(
        (__attribute__((address_space(1))) void*)(g),
        (__attribute__((address_space(3))) void*)(l), 16, 0, 0);
}

// Packed tile format (4 KB = 256 granules of 16 B) for a 64(row) x 32(k) tile:
//   granule(q, r) = q*64 + r holds elements [row=r][k = q*8 .. q*8+7]
// Fragment read hits 16 consecutive granules per quad-phase -> conflict-free
// ds_read_b128 (R8-R12: SQ_LDS_BANK_CONFLICT == 0).

// prep_fused grid: [0,2000) softmax | [2000,3024) transpose |
// [3024,3120) Sp63 zero-fill (96 blocks x 2048 elems) | [3120,4320) W-gen
#define ZERO_BLK  96
#define PW_BLOCKS 1200
#define PREP_BLOCKS (N_NODES + 1024 + ZERO_BLK + PW_BLOCKS)

// ---------------------------------------------------------------------------
// Kernel A (fused): softmax -> Sp packed | x transpose-pack | Sp63 zero |
// W-gen (from RAW wp/emb inputs -> no intra-kernel dependency).
// ---------------------------------------------------------------------------
__global__ __launch_bounds__(256) void prep_fused(
    const float* __restrict__ nv1, const float* __restrict__ nv2,
    bf16* __restrict__ Sp,
    const float* __restrict__ X, bf16* __restrict__ Xtp, bf16* __restrict__ Xbf,
    const float* __restrict__ wp, const float* __restrict__ emb,
    bf16* __restrict__ W, bf16* __restrict__ Sp63)
{
    const int bid = blockIdx.x;
    const int tid = threadIdx.x;

    if (bid < N_NODES) {
        // ----- softmax(relu(nv1@nv2)) row -> packed Sp tiles -----
        const int row = bid;
        const int j0  = tid * 8;
        __shared__ float sa[EMB];
        __shared__ float wred[4];
        __shared__ float bcast;
        if (tid < EMB) sa[tid] = nv1[row * EMB + tid];
        __syncthreads();

        const bool active = (tid < 250);
        float v[8] = {0,0,0,0,0,0,0,0};
        if (active) {
#pragma unroll
            for (int d = 0; d < EMB; ++d) {
                const float sd = sa[d];
                const float4 q0 = *(const float4*)&nv2[d * N_NODES + j0];
                const float4 q1 = *(const float4*)&nv2[d * N_NODES + j0 + 4];
                v[0] += sd * q0.x; v[1] += sd * q0.y; v[2] += sd * q0.z; v[3] += sd * q0.w;
                v[4] += sd * q1.x; v[5] += sd * q1.y; v[6] += sd * q1.z; v[7] += sd * q1.w;
            }
        }
        float lmax = 0.0f;
#pragma unroll
        for (int jj = 0; jj < 8; ++jj) { v[jj] = fmaxf(v[jj], 0.0f); lmax = fmaxf(lmax, v[jj]); }
#pragma unroll
        for (int off = 32; off > 0; off >>= 1)
            lmax = fmaxf(lmax, __shfl_down(lmax, off, 64));
        if ((tid & 63) == 0) wred[tid >> 6] = lmax;
        __syncthreads();
        if (tid == 0) bcast = fmaxf(fmaxf(wred[0], wred[1]), fmaxf(wred[2], wred[3]));
        __syncthreads();
        const float rmax = bcast;

        float lsum = 0.0f;
        if (active) {
#pragma unroll
            for (int jj = 0; jj < 8; ++jj) { v[jj] = __expf(v[jj] - rmax); lsum += v[jj]; }
        }
#pragma unroll
        for (int off = 32; off > 0; off >>= 1)
            lsum += __shfl_down(lsum, off, 64);
        if ((tid & 63) == 0) wred[tid >> 6] = lsum;
        __syncthreads();
        if (tid == 0) bcast = wred[0] + wred[1] + wred[2] + wred[3];
        __syncthreads();
        const float inv = 1.0f / bcast;

        if (tid < 252) {   // threads 250,251 write the k 2000..2015 zero pad
            bf16x8 pk;
#pragma unroll
            for (int jj = 0; jj < 8; ++jj)
                pk[jj] = (bf16)(active ? v[jj] * inv : 0.0f);
            const int kb = j0 >> 5, q = (j0 >> 3) & 3;
            const int nt = row >> 6, r = row & 63;
            *(bf16x8*)&Sp[((size_t)(kb * 32 + nt) * 256 + q * 64 + r) * 8] = pk;
        }
    } else if (bid < N_NODES + 1024) {
        // ----- x [b][m][c] fp32 -> xTp packed + xbf row-major bf16 -----
        const int t  = bid - N_NODES;
        const int b  = t >> 5;
        const int m0 = (t & 31) * 64;
        __shared__ bf16 T[64][72];
#pragma unroll
        for (int i = 0; i < 4; ++i) {
            int idx = i * 256 + tid;
            int r  = idx >> 4;
            int c4 = (idx & 15) * 4;
            int m  = m0 + r;
            float4 v = make_float4(0.f, 0.f, 0.f, 0.f);
            if (m < N_NODES)
                v = *(const float4*)&X[((size_t)b * N_NODES + m) * DIM + c4];
            bf16x4pk pk;
            pk.v[0] = (bf16)v.x; pk.v[1] = (bf16)v.y;
            pk.v[2] = (bf16)v.z; pk.v[3] = (bf16)v.w;
            if (m < N_NODES)
                *(bf16x4pk*)&Xbf[((size_t)b * N_NODES + m) * DIM + c4] = pk;
            T[c4 + 0][r] = pk.v[0];
            T[c4 + 1][r] = pk.v[1];
            T[c4 + 2][r] = pk.v[2];
            T[c4 + 3][r] = pk.v[3];
        }
        __syncthreads();
#pragma unroll
        for (int i = 0; i < 2; ++i) {
            int idx = i * 256 + tid;
            int c   = idx >> 3;
            int mch = idx & 7;
            int kb  = (m0 >> 5) + (mch >> 2);
            if (kb < KB) {
                int q = mch & 3;
                bf16x8 vv = *(const bf16x8*)&T[c][mch * 8];
                *(bf16x8*)&Xtp[((size_t)(b * KB3 + kb) * 256 + q * 64 + c) * 8] = vv;
            }
        }
    } else if (bid < N_NODES + 1024 + ZERO_BLK) {
        // ----- zero-fill Sp slabs 63..65 (8 bf16 per thread) -----
        const int idx = (bid - N_NODES - 1024) * 256 + tid;
        bf16x8 z;
#pragma unroll
        for (int e = 0; e < 8; ++e) z[e] = (bf16)0.0f;
        *(bf16x8*)&Sp63[(size_t)idx * 8] = z;
    } else {
        // ----- W-gen from RAW inputs: W[n][col] = sum_d emb[n][d]*wp[d][...]
        // col = o*KI + (cheb*64 + i); B-frag d = quad*8+e (only quad<2 real).
        // Body identical to the R4-proven prep_W (one Cs, two barriers/group).
        __shared__ bf16 CsW[16][264];
        const int pid     = bid - (N_NODES + 1024 + ZERO_BLK);
        const int colbase = (pid % 48) * 256;
        const int ng0     = (pid / 48) * 5;

        const int lane = tid & 63, wave = tid >> 6;
        const int l15 = lane & 15, quad = lane >> 4;

        bf16x8 bfr[4];
#pragma unroll
        for (int ct = 0; ct < 4; ++ct) {
            const int col  = colbase + wave * 64 + ct * 16 + l15;
            const int o    = col / KI;
            const int kk   = col - o * KI;
            const int cheb = kk >> 6, ii = kk & 63;
            bf16x8 v;
#pragma unroll
            for (int e = 0; e < 8; ++e) v[e] = (bf16)0.0f;
            if (quad < 2) {
                const float* base = &wp[((((quad * 8) * 3 + cheb) * 64 + ii) * 64) + o];
#pragma unroll
                for (int e = 0; e < 8; ++e)
                    v[e] = (bf16)base[(size_t)e * (3 * 64 * 64)];
            }
            bfr[ct] = v;
        }
        bf16x8 afs[5];
#pragma unroll
        for (int g = 0; g < 5; ++g) {
            bf16x8 v;
#pragma unroll
            for (int e = 0; e < 8; ++e) v[e] = (bf16)0.0f;
            if (quad < 2) {
                const float* base = &emb[((ng0 + g) * 16 + l15) * EMB + quad * 8];
#pragma unroll
                for (int e = 0; e < 8; ++e) v[e] = (bf16)base[e];
            }
            afs[g] = v;
        }
        const f32x4 zero = {};
#pragma unroll
        for (int g = 0; g < 5; ++g) {
            const int n0 = (ng0 + g) * 16;
#pragma unroll
            for (int ct = 0; ct < 4; ++ct) {
                f32x4 acc = __builtin_amdgcn_mfma_f32_16x16x32_bf16(afs[g], bfr[ct], zero, 0, 0, 0);
#pragma unroll
                for (int r = 0; r < 4; ++r)
                    CsW[quad * 4 + r][wave * 64 + ct * 16 + l15] = (bf16)acc[r];
            }
            __syncthreads();
            {
                const int row = tid >> 4;
                const int c16 = (tid & 15) * 16;
                bf16x8 v0 = *(const bf16x8*)&CsW[row][c16];
                bf16x8 v1 = *(const bf16x8*)&CsW[row][c16 + 8];
                bf16* dst = &W[(size_t)(n0 + row) * WCOLS + colbase + c16];
                *(bf16x8*)dst       = v0;
                *(bf16x8*)(dst + 8) = v1;
            }
            __syncthreads();   // CsW fully consumed before next group's MFMA
        }
    }
}

// ---------------------------------------------------------------------------
// Kernel 3: spmm_pipe — depth-3 ring + counted vmcnt (T3/T4 port).
// R4 PMC: 2-buffer + __syncthreads (vmcnt(0) drain/stage) ran 46 us at
// MfmaUtil 15% / hbm 26% — latency-bound on the per-stage DMA round-trip.
// Ring of 3 x (16 KB A + 8 KB B); stages 2 kb each, 33 stages.
// Epoch s: waitcnt vmcnt(6) [stage s landed, s+1 in flight] -> raw s_barrier
// -> sched_barrier(0) [pin ds_reads below] -> issue stage s+2 -> ds_read
// buf[s%3] -> 16 MFMA. buf(s+2)%3 is disjoint from {s,s+1}%3 and its prior
// reader (epoch s-1) is separated by barrier s -> race-free. Final epoch
// drains vmcnt(0). Prefetch window: 2 full epochs instead of <1.
// ---------------------------------------------------------------------------
__global__ __launch_bounds__(256, 2) void spmm_pipe(
    const bf16* __restrict__ Ap, const bf16* __restrict__ Btp,
    bf16* __restrict__ Ybf, bf16* __restrict__ Ytp, int write_ytp)
{
    const int i = blockIdx.x;            // 0..511
    const int kx = i & 7, j = i >> 3;    // kx = XCD (dispatch round-robin)
    const int ntB = (j & 7) + 8 * (kx & 1);
    const int b   = ((j >> 3) << 2) + (kx >> 1);
    const int n0  = ntB * 128;
    const int tid = threadIdx.x;
    const int lane = tid & 63, wave = tid >> 6;
    const int l15 = lane & 15, quad = lane >> 4;

    __shared__ bf16 As[3][2 * 4096];   // 3 x 16 KB (128 rows x 2x32 k)
    __shared__ bf16 Bs[3][2 * 2048];   // 3 x  8 KB ( 64 cols x 2x32 k)

    const bf16* aslab = Ap  + (size_t)(ntB * 2) * 2048 + tid * 8;  // + kb*65536
    const bf16* bslab = Btp + (size_t)(b * KB3) * 2048 + tid * 8;  // + kb*2048

    // 6 gl_lds16 per wave per stage (vmcnt += 6)
#define STAGE(buf, s_) {                                               \
        _Pragma("unroll")                                              \
        for (int jj = 0; jj < 2; ++jj) {                               \
            const bf16* pa = aslab + (size_t)(2 * (s_) + jj) * (32 * 2048); \
            const bf16* pb = bslab + (size_t)(2 * (s_) + jj) * 2048;   \
            gl_lds16(pa,        &As[buf][jj * 4096 + tid * 8]);        \
            gl_lds16(pa + 2048, &As[buf][jj * 4096 + 2048 + tid * 8]); \
            gl_lds16(pb,        &Bs[buf][jj * 2048 + tid * 8]); } }

    f32x4 acc[2][4] = {};
    const int ga = (wave >> 1) * 256 + quad * 64 + (wave & 1) * 32; // A granule base
    const int gb = quad * 64;                                       // B granule base

    STAGE(0, 0);
    STAGE(1, 1);
#pragma unroll 1
    for (int s = 0; s < 33; ++s) {
        const int cur = s % 3;
        if (s + 1 < 33) {
            asm volatile("s_waitcnt vmcnt(6)" ::: "memory");  // stage s landed
        } else {
            asm volatile("s_waitcnt vmcnt(0)" ::: "memory");  // drain last
        }
        __builtin_amdgcn_s_barrier();          // raw barrier: no vmcnt drain
        __builtin_amdgcn_sched_barrier(0);     // pin ds_reads below barrier
        if (s + 2 < 33) {
            const int nxt = (cur + 2 >= 3) ? cur - 1 : cur + 2;   // (s+2)%3
            STAGE(nxt, s + 2);
        }
        bf16x8 af[2][2], bfr[2][4];
#pragma unroll
        for (int jj = 0; jj < 2; ++jj) {
#pragma unroll
            for (int t = 0; t < 2; ++t)
                af[jj][t]  = *(const bf16x8*)&As[cur][jj * 4096 + (ga + t * 16 + l15) * 8];
#pragma unroll
            for (int t = 0; t < 4; ++t)
                bfr[jj][t] = *(const bf16x8*)&Bs[cur][jj * 2048 + (gb + t * 16 + l15) * 8];
        }
#pragma unroll
        for (int jj = 0; jj < 2; ++jj)
#pragma unroll
            for (int rt = 0; rt < 2; ++rt)
#pragma unroll
                for (int ct = 0; ct < 4; ++ct)
                    acc[rt][ct] = __builtin_amdgcn_mfma_f32_16x16x32_bf16(
                        af[jj][rt], bfr[jj][ct], acc[rt][ct], 0, 0, 0);
    }
#undef STAGE

    // Epilogue. C/D layout: col = lane&15, row = quad*4 + reg
#pragma unroll
    for (int rt = 0; rt < 2; ++rt) {
        const int nbase = n0 + wave * 32 + rt * 16 + quad * 4;
#pragma unroll
        for (int ct = 0; ct < 4; ++ct) {
            const int c = ct * 16 + l15;
#pragma unroll
            for (int r = 0; r < 4; ++r) {
                int n = nbase + r;
                if (n < N_NODES)
                    Ybf[((size_t)b * N_NODES + n) * DIM + c] = (bf16)acc[rt][ct][r];
            }
            if (write_ytp && nbase + 4 <= N_NODES) {
                const int kb2 = nbase >> 5;
                const int kq  = (nbase & 31) >> 3;
                const int j4  = nbase & 7;       // 0 or 4
                bf16x4pk pk;
                pk.v[0] = (bf16)acc[rt][ct][0];
                pk.v[1] = (bf16)acc[rt][ct][1];
                pk.v[2] = (bf16)acc[rt][ct][2];
                pk.v[3] = (bf16)acc[rt][ct][3];
                *(bf16x4pk*)&Ytp[((size_t)(b * KB3 + kb2) * 256 + kq * 64 + c) * 8 + j4] = pk;
            }
        }
    }
}

// ---------------------------------------------------------------------------
// Kernel 5: per-node combine (bf16 inputs) — proven baseline form.
// ---------------------------------------------------------------------------
__global__ __launch_bounds__(256) void combine_node(
    const bf16* __restrict__ xbf, const bf16* __restrict__ y1bf,
    const bf16* __restrict__ y2bf, const float* __restrict__ emb,
    const float* __restrict__ bp, const bf16* __restrict__ W,
    float* __restrict__ out)
{
    const int n   = blockIdx.x;
    const int tid = threadIdx.x;
    const int lane = tid & 63, wave = tid >> 6;
    const int l15 = lane & 15, quad = lane >> 4;

    __shared__ bf16 As[BATCH][200];
    __shared__ bf16 Ws[DIM][200];
    __shared__ float bias_s[DIM];
    __shared__ float emb_s[EMB];

    if (tid < EMB) emb_s[tid] = emb[n * EMB + tid];

    {
        const int b  = tid >> 3;
        const int c8 = (tid & 7) * 8;
        const size_t base = ((size_t)b * N_NODES + n) * DIM + c8;
        bf16x8 vx = *(const bf16x8*)&xbf [base];
        bf16x8 v1 = *(const bf16x8*)&y1bf[base];
        bf16x8 v2 = *(const bf16x8*)&y2bf[base];
        bf16x8 p2;
#pragma unroll
        for (int e = 0; e < 8; ++e)
            p2[e] = (bf16)(2.0f * (float)v2[e] - (float)vx[e]);
        *(bf16x8*)&As[b][c8]       = vx;
        *(bf16x8*)&As[b][64 + c8]  = v1;
        *(bf16x8*)&As[b][128 + c8] = p2;
    }
    {
        const bf16* Wn = W + (size_t)n * WCOLS;
#pragma unroll
        for (int jj = 0; jj < 6; ++jj) {
            int chunk = jj * 256 + tid;
            int o  = chunk / 24;
            int kc = chunk - o * 24;
            bf16x8 v = *(const bf16x8*)&Wn[(size_t)chunk * 8];
            *(bf16x8*)&Ws[o][kc * 8] = v;
        }
    }
    __syncthreads();

    if (tid < DIM) {
        float s = 0.0f;
#pragma unroll
        for (int d = 0; d < EMB; ++d) s += emb_s[d] * bp[d * DIM + tid];
        bias_s[tid] = s;
    }

    bf16x8 af[2][6];
#pragma unroll
    for (int mt = 0; mt < 2; ++mt)
#pragma unroll
        for (int ks = 0; ks < 6; ++ks)
            af[mt][ks] = *(const bf16x8*)&As[mt * 16 + l15][ks * 32 + quad * 8];

    f32x4 acc[2] = {};
#pragma unroll
    for (int ks = 0; ks < 6; ++ks) {
        bf16x8 bfr = *(const bf16x8*)&Ws[wave * 16 + l15][ks * 32 + quad * 8];
        acc[0] = __builtin_amdgcn_mfma_f32_16x16x32_bf16(af[0][ks], bfr, acc[0], 0, 0, 0);
        acc[1] = __builtin_amdgcn_mfma_f32_16x16x32_bf16(af[1][ks], bfr, acc[1], 0, 0, 0);
    }
    __syncthreads();

    const int o = wave * 16 + l15;
    const float bv = bias_s[o];
#pragma unroll
    for (int mt = 0; mt < 2; ++mt)
#pragma unroll
        for (int r = 0; r < 4; ++r) {
            int b = mt * 16 + quad * 4 + r;
            out[((size_t)b * N_NODES + n) * DIM + o] = acc[mt][r] + bv;
        }
}

// ---------------------------------------------------------------------------
extern "C" void kernel_launch(void* const* d_in, const int* in_sizes, int n_in,
                              void* d_out, int out_size, void* d_ws, size_t ws_size,
                              hipStream_t stream) {
    const float* x   = (const float*)d_in[0];  // [32,2000,64]
    const float* emb = (const float*)d_in[1];  // [2000,16]
    const float* nv1 = (const float*)d_in[2];  // [2000,16]
    const float* nv2 = (const float*)d_in[3];  // [16,2000]
    const float* wp  = (const float*)d_in[4];  // [16,3,64,64]
    const float* bp  = (const float*)d_in[5];  // [16,64]
    float* out = (float*)d_out;                // [32,2000,64]

    char* w = (char*)d_ws;
    bf16* Sp   = (bf16*)w;  w += (size_t)KB3 * NP * 32 * 2;           //  8.65 MB
    bf16* xTp  = (bf16*)w;  w += (size_t)BATCH * KB3 * DIM * 32 * 2;  //  8.65 MB
    bf16* y1Tp = (bf16*)w;  w += (size_t)BATCH * KB3 * DIM * 32 * 2;  //  8.65 MB
    bf16* xbf  = (bf16*)w;  w += (size_t)BATCH * N_NODES * DIM * 2;   //  8.19 MB
    bf16* y1bf = (bf16*)w;  w += (size_t)BATCH * N_NODES * DIM * 2;   //  8.19 MB
    bf16* y2bf = (bf16*)w;  w += (size_t)BATCH * N_NODES * DIM * 2;   //  8.19 MB
    bf16* W    = (bf16*)w;                                            // 49.15 MB

    prep_fused<<<PREP_BLOCKS, 256, 0, stream>>>(
        nv1, nv2, Sp, x, xTp, xbf, wp, emb, W,
        Sp + (size_t)63 * NP * 32);
    spmm_pipe<<<512, 256, 0, stream>>>(Sp, xTp,  y1bf, y1Tp, 1);
    spmm_pipe<<<512, 256, 0, stream>>>(Sp, y1Tp, y2bf, y1Tp, 0);
    combine_node<<<N_NODES, 256, 0, stream>>>(xbf, y1bf, y2bf, emb, bp, W, out);
}

// Round 6
// 165.322 us; speedup vs baseline: 1.1508x; 1.1508x over previous
//
#include <hip/hip_runtime.h>

#define N_NODES 2000
#define NP      2048    // Sp n-dim padding
#define KB      63      // real k-blocks (k = 2000 padded to 2016 in-block)
#define KB3     66      // padded k-blocks: slabs 63..65 of Sp zero-filled (A=0)
#define BATCH   32
#define DIM     64      // DIM_IN == DIM_OUT
#define EMB     16
#define KI      192     // CHEB_K * DIM_IN
#define WCOLS   12288   // DIM_OUT * KI

typedef __bf16 bf16;
typedef __attribute__((ext_vector_type(8))) __bf16 bf16x8;
typedef __attribute__((ext_vector_type(4))) float  f32x4;

struct alignas(8) bf16x4pk { bf16 v[4]; };

// Async global->LDS DMA, 16 B per lane (lane-contiguous within each wave).
__device__ __forceinline__ void gl_lds16(const bf16* g, bf16* l) {
    __builtin_amdgcn_global_load_lds(
        (__attribute__((address_space(1))) void*)(g),
        (__attribute__((address_space(3))) void*)(l), 16, 0, 0);
}

// Packed tile format (4 KB = 256 granules of 16 B) for a 64(row) x 32(k) tile:
//   granule(q, r) = q*64 + r holds elements [row=r][k = q*8 .. q*8+7]
// Fragment read hits 16 consecutive granules per quad-phase -> conflict-free
// ds_read_b128 (R8-R12: SQ_LDS_BANK_CONFLICT == 0).

#define Z0   (WCOLS * 32)
#define Z1   (Z0 + N_NODES * 32)
#define Z2   (Z1 + 3 * NP * 32)
// fused-prep grid: [0,2000) softmax rows | [2000,3024) transpose tiles |
// [3024, 3024+2554) prep_small chunks  (Z2/256 == 2554 exactly)
#define PREP_SM_BLK   2554
#define PREP_BLOCKS   (N_NODES + 1024 + PREP_SM_BLK)

// prep_W coarse blocks: 48 colbases x 25 strips (5 n-groups each) = 1200
#define PW_BLOCKS 1200

// ---------------------------------------------------------------------------
// Kernel A (fused): softmax -> Sp packed | x transpose-pack | wpT2/embp/zero
// (R4-proven form: W-gen reads the PACKED wpT2/embp — R5's raw-input W-gen
//  was -35 us from uncoalesced scalar wp loads.)
// ---------------------------------------------------------------------------
__global__ __launch_bounds__(256) void prep_fused(
    const float* __restrict__ nv1, const float* __restrict__ nv2,
    bf16* __restrict__ Sp,
    const float* __restrict__ X, bf16* __restrict__ Xtp, bf16* __restrict__ Xbf,
    const float* __restrict__ wp, const float* __restrict__ emb,
    bf16* __restrict__ wpT2, bf16* __restrict__ embp, bf16* __restrict__ Sp63)
{
    const int bid = blockIdx.x;
    const int tid = threadIdx.x;

    if (bid < N_NODES) {
        // ----- softmax(relu(nv1@nv2)) row -> packed Sp tiles -----
        const int row = bid;
        const int j0  = tid * 8;
        __shared__ float sa[EMB];
        __shared__ float wred[4];
        __shared__ float bcast;
        if (tid < EMB) sa[tid] = nv1[row * EMB + tid];
        __syncthreads();

        const bool active = (tid < 250);
        float v[8] = {0,0,0,0,0,0,0,0};
        if (active) {
#pragma unroll
            for (int d = 0; d < EMB; ++d) {
                const float sd = sa[d];
                const float4 q0 = *(const float4*)&nv2[d * N_NODES + j0];
                const float4 q1 = *(const float4*)&nv2[d * N_NODES + j0 + 4];
                v[0] += sd * q0.x; v[1] += sd * q0.y; v[2] += sd * q0.z; v[3] += sd * q0.w;
                v[4] += sd * q1.x; v[5] += sd * q1.y; v[6] += sd * q1.z; v[7] += sd * q1.w;
            }
        }
        float lmax = 0.0f;
#pragma unroll
        for (int jj = 0; jj < 8; ++jj) { v[jj] = fmaxf(v[jj], 0.0f); lmax = fmaxf(lmax, v[jj]); }
#pragma unroll
        for (int off = 32; off > 0; off >>= 1)
            lmax = fmaxf(lmax, __shfl_down(lmax, off, 64));
        if ((tid & 63) == 0) wred[tid >> 6] = lmax;
        __syncthreads();
        if (tid == 0) bcast = fmaxf(fmaxf(wred[0], wred[1]), fmaxf(wred[2], wred[3]));
        __syncthreads();
        const float rmax = bcast;

        float lsum = 0.0f;
        if (active) {
#pragma unroll
            for (int jj = 0; jj < 8; ++jj) { v[jj] = __expf(v[jj] - rmax); lsum += v[jj]; }
        }
#pragma unroll
        for (int off = 32; off > 0; off >>= 1)
            lsum += __shfl_down(lsum, off, 64);
        if ((tid & 63) == 0) wred[tid >> 6] = lsum;
        __syncthreads();
        if (tid == 0) bcast = wred[0] + wred[1] + wred[2] + wred[3];
        __syncthreads();
        const float inv = 1.0f / bcast;

        if (tid < 252) {   // threads 250,251 write the k 2000..2015 zero pad
            bf16x8 pk;
#pragma unroll
            for (int jj = 0; jj < 8; ++jj)
                pk[jj] = (bf16)(active ? v[jj] * inv : 0.0f);
            const int kb = j0 >> 5, q = (j0 >> 3) & 3;
            const int nt = row >> 6, r = row & 63;
            *(bf16x8*)&Sp[((size_t)(kb * 32 + nt) * 256 + q * 64 + r) * 8] = pk;
        }
    } else if (bid < N_NODES + 1024) {
        // ----- x [b][m][c] fp32 -> xTp packed + xbf row-major bf16 -----
        const int t  = bid - N_NODES;
        const int b  = t >> 5;
        const int m0 = (t & 31) * 64;
        __shared__ bf16 T[64][72];
#pragma unroll
        for (int i = 0; i < 4; ++i) {
            int idx = i * 256 + tid;
            int r  = idx >> 4;
            int c4 = (idx & 15) * 4;
            int m  = m0 + r;
            float4 v = make_float4(0.f, 0.f, 0.f, 0.f);
            if (m < N_NODES)
                v = *(const float4*)&X[((size_t)b * N_NODES + m) * DIM + c4];
            bf16x4pk pk;
            pk.v[0] = (bf16)v.x; pk.v[1] = (bf16)v.y;
            pk.v[2] = (bf16)v.z; pk.v[3] = (bf16)v.w;
            if (m < N_NODES)
                *(bf16x4pk*)&Xbf[((size_t)b * N_NODES + m) * DIM + c4] = pk;
            T[c4 + 0][r] = pk.v[0];
            T[c4 + 1][r] = pk.v[1];
            T[c4 + 2][r] = pk.v[2];
            T[c4 + 3][r] = pk.v[3];
        }
        __syncthreads();
#pragma unroll
        for (int i = 0; i < 2; ++i) {
            int idx = i * 256 + tid;
            int c   = idx >> 3;
            int mch = idx & 7;
            int kb  = (m0 >> 5) + (mch >> 2);
            if (kb < KB) {
                int q = mch & 3;
                bf16x8 vv = *(const bf16x8*)&T[c][mch * 8];
                *(bf16x8*)&Xtp[((size_t)(b * KB3 + kb) * 256 + q * 64 + c) * 8] = vv;
            }
        }
    } else {
        // ----- wpT2 / embp pack + zero-fill Sp slabs 63..65 -----
        int idx = (bid - N_NODES - 1024) * 256 + tid;
        if (idx < Z0) {
            int col = idx >> 5, d = idx & 31;
            int o  = col / KI;
            int kk = col - o * KI;
            int cheb = kk >> 6, i = kk & 63;
            float v = (d < EMB) ? wp[(((d * 3 + cheb) * 64 + i) * 64) + o] : 0.0f;
            wpT2[idx] = (bf16)v;
        } else if (idx < Z1) {
            int j = idx - Z0;
            int n = j >> 5, d = j & 31;
            float v = (d < EMB) ? emb[n * EMB + d] : 0.0f;
            embp[j] = (bf16)v;
        } else if (idx < Z2) {
            Sp63[idx - Z1] = (bf16)0.0f;
        }
    }
}

// ---------------------------------------------------------------------------
// Kernel 3 (MERGED): spmm ring-4 pipeline + prep_W colocated.
// R4 A/B target: same dispatch shape ran 46.4 us with the 2-buffer
// drain-per-stage structure (MfmaUtil 15%, hbm 26% -> latency-bound on the
// per-stage DMA round-trip; prefetch window < 1 epoch).
// R6: ring of 4 x 1-kb stages (4 x (8KB A + 4KB B) = 48 KB exactly, still
// 3 blocks/CU so W-gen colocation is preserved). Per stage: 3 DMA/wave.
// Epoch s: vmcnt(6) [stage s landed; s+1,s+2 in flight] -> raw s_barrier
// -> sched_barrier(0) -> issue stage s+3 -> 6x ds_read -> 8 MFMA.
// Prefetch window = 3 epochs. Race check: buf (s+3)&3 last read in epoch
// s-1, separated by barrier s. Sync pattern HW-validated in R5 (passed).
// ---------------------------------------------------------------------------
__global__ __launch_bounds__(256, 3) void spmm_pipe4(
    const bf16* __restrict__ Ap, const bf16* __restrict__ Btp,
    bf16* __restrict__ Ybf, bf16* __restrict__ Ytp,
    const bf16* __restrict__ embp, const bf16* __restrict__ wpT2,
    bf16* __restrict__ W, int write_ytp)
{
    __shared__ __align__(16) char smem[49152];   // 48 KB: union of both roles
    const int bid  = blockIdx.x;
    const int tid  = threadIdx.x;
    const int lane = tid & 63, wave = tid >> 6;
    const int l15  = lane & 15, quad = lane >> 4;

    if (bid < 512) {
        // ================= spmm role (ring-4, counted vmcnt) ==============
        bf16* As = (bf16*)smem;             // 4 bufs x 4096 elems (8 KB)
        bf16* Bs = (bf16*)(smem + 32768);   // 4 bufs x 2048 elems (4 KB)

        const int kx = bid & 7, j = bid >> 3;   // kx = XCD (dispatch round-robin)
        const int ntB = (j & 7) + 8 * (kx & 1);
        const int b   = ((j >> 3) << 2) + (kx >> 1);
        const int n0  = ntB * 128;

        const bf16* aslab = Ap  + (size_t)(ntB * 2) * 2048 + tid * 8;  // + kb*65536
        const bf16* bslab = Btp + (size_t)(b * KB3) * 2048 + tid * 8;  // + kb*2048

        // 3 gl_lds16 per wave per stage (vmcnt += 3)
#define STAGE(buf, s_) {                                               \
        const bf16* pa = aslab + (size_t)(s_) * (32 * 2048);           \
        const bf16* pb = bslab + (size_t)(s_) * 2048;                  \
        gl_lds16(pa,        &As[(buf) * 4096 + tid * 8]);              \
        gl_lds16(pa + 2048, &As[(buf) * 4096 + 2048 + tid * 8]);       \
        gl_lds16(pb,        &Bs[(buf) * 2048 + tid * 8]); }

        f32x4 acc[2][4] = {};
        const int ga = (wave >> 1) * 256 + quad * 64 + (wave & 1) * 32; // A granule base
        const int gb = quad * 64;                                       // B granule base

        STAGE(0, 0);
        STAGE(1, 1);
        STAGE(2, 2);
#pragma unroll 1
        for (int s = 0; s < 66; ++s) {
            const int cur = s & 3;
            if (s < 64) {
                asm volatile("s_waitcnt vmcnt(6)" ::: "memory");  // stage s landed
            } else if (s == 64) {
                asm volatile("s_waitcnt vmcnt(3)" ::: "memory");
            } else {
                asm volatile("s_waitcnt vmcnt(0)" ::: "memory");
            }
            __builtin_amdgcn_s_barrier();          // raw barrier: no vmcnt drain
            __builtin_amdgcn_sched_barrier(0);     // pin ds_reads below barrier
            if (s + 3 < 66) STAGE((s + 3) & 3, s + 3);
            bf16x8 af[2], bfr[4];
#pragma unroll
            for (int t = 0; t < 2; ++t)
                af[t]  = *(const bf16x8*)&As[cur * 4096 + (ga + t * 16 + l15) * 8];
#pragma unroll
            for (int t = 0; t < 4; ++t)
                bfr[t] = *(const bf16x8*)&Bs[cur * 2048 + (gb + t * 16 + l15) * 8];
#pragma unroll
            for (int rt = 0; rt < 2; ++rt)
#pragma unroll
                for (int ct = 0; ct < 4; ++ct)
                    acc[rt][ct] = __builtin_amdgcn_mfma_f32_16x16x32_bf16(
                        af[rt], bfr[ct], acc[rt][ct], 0, 0, 0);
        }
#undef STAGE

        // Epilogue. C/D layout: col = lane&15, row = quad*4 + reg
#pragma unroll
        for (int rt = 0; rt < 2; ++rt) {
            const int nbase = n0 + wave * 32 + rt * 16 + quad * 4;
#pragma unroll
            for (int ct = 0; ct < 4; ++ct) {
                const int c = ct * 16 + l15;
#pragma unroll
                for (int r = 0; r < 4; ++r) {
                    int n = nbase + r;
                    if (n < N_NODES)
                        Ybf[((size_t)b * N_NODES + n) * DIM + c] = (bf16)acc[rt][ct][r];
                }
                if (write_ytp && nbase + 4 <= N_NODES) {
                    const int kb2 = nbase >> 5;
                    const int kq  = (nbase & 31) >> 3;
                    const int j4  = nbase & 7;       // 0 or 4
                    bf16x4pk pk;
                    pk.v[0] = (bf16)acc[rt][ct][0];
                    pk.v[1] = (bf16)acc[rt][ct][1];
                    pk.v[2] = (bf16)acc[rt][ct][2];
                    pk.v[3] = (bf16)acc[rt][ct][3];
                    *(bf16x4pk*)&Ytp[((size_t)(b * KB3 + kb2) * 256 + kq * 64 + c) * 8 + j4] = pk;
                }
            }
        }
    } else {
        // ================= prep_W role (coarse, R4-proven body) ============
        // W[n][col] = sum_d embp[n][d] * wpT2[col][d]  (bf16 out)
        bf16 (*Cs)[264] = (bf16(*)[264])smem;    // 16 x 264 x 2B = 8.4 KB

        const int pid     = bid - 512;
        const int colbase = (pid % 48) * 256;
        const int ng0     = (pid / 48) * 5;

        bf16x8 bfr[4];
#pragma unroll
        for (int ct = 0; ct < 4; ++ct) {
            const int col = colbase + wave * 64 + ct * 16 + l15;
            bfr[ct] = *(const bf16x8*)&wpT2[(size_t)col * 32 + quad * 8];
        }
        bf16x8 afs[5];
#pragma unroll
        for (int g = 0; g < 5; ++g)
            afs[g] = *(const bf16x8*)&embp[(size_t)((ng0 + g) * 16 + l15) * 32 + quad * 8];
        const f32x4 zero = {};

#pragma unroll
        for (int g = 0; g < 5; ++g) {
            const int n0 = (ng0 + g) * 16;
#pragma unroll
            for (int ct = 0; ct < 4; ++ct) {
                f32x4 acc = __builtin_amdgcn_mfma_f32_16x16x32_bf16(afs[g], bfr[ct], zero, 0, 0, 0);
#pragma unroll
                for (int r = 0; r < 4; ++r)
                    Cs[quad * 4 + r][wave * 64 + ct * 16 + l15] = (bf16)acc[r];
            }
            __syncthreads();
            {
                const int row = tid >> 4;
                const int c16 = (tid & 15) * 16;
                bf16x8 v0 = *(const bf16x8*)&Cs[row][c16];
                bf16x8 v1 = *(const bf16x8*)&Cs[row][c16 + 8];
                bf16* dst = &W[(size_t)(n0 + row) * WCOLS + colbase + c16];
                *(bf16x8*)dst       = v0;
                *(bf16x8*)(dst + 8) = v1;
            }
            __syncthreads();   // Cs fully consumed before next group's MFMA
        }
    }
}

// ---------------------------------------------------------------------------
// Kernel 5: per-node combine (bf16 inputs) — proven baseline form.
// ---------------------------------------------------------------------------
__global__ __launch_bounds__(256) void combine_node(
    const bf16* __restrict__ xbf, const bf16* __restrict__ y1bf,
    const bf16* __restrict__ y2bf, const float* __restrict__ emb,
    const float* __restrict__ bp, const bf16* __restrict__ W,
    float* __restrict__ out)
{
    const int n   = blockIdx.x;
    const int tid = threadIdx.x;
    const int lane = tid & 63, wave = tid >> 6;
    const int l15 = lane & 15, quad = lane >> 4;

    __shared__ bf16 As[BATCH][200];
    __shared__ bf16 Ws[DIM][200];
    __shared__ float bias_s[DIM];
    __shared__ float emb_s[EMB];

    if (tid < EMB) emb_s[tid] = emb[n * EMB + tid];

    {
        const int b  = tid >> 3;
        const int c8 = (tid & 7) * 8;
        const size_t base = ((size_t)b * N_NODES + n) * DIM + c8;
        bf16x8 vx = *(const bf16x8*)&xbf [base];
        bf16x8 v1 = *(const bf16x8*)&y1bf[base];
        bf16x8 v2 = *(const bf16x8*)&y2bf[base];
        bf16x8 p2;
#pragma unroll
        for (int e = 0; e < 8; ++e)
            p2[e] = (bf16)(2.0f * (float)v2[e] - (float)vx[e]);
        *(bf16x8*)&As[b][c8]       = vx;
        *(bf16x8*)&As[b][64 + c8]  = v1;
        *(bf16x8*)&As[b][128 + c8] = p2;
    }
    {
        const bf16* Wn = W + (size_t)n * WCOLS;
#pragma unroll
        for (int jj = 0; jj < 6; ++jj) {
            int chunk = jj * 256 + tid;
            int o  = chunk / 24;
            int kc = chunk - o * 24;
            bf16x8 v = *(const bf16x8*)&Wn[(size_t)chunk * 8];
            *(bf16x8*)&Ws[o][kc * 8] = v;
        }
    }
    __syncthreads();

    if (tid < DIM) {
        float s = 0.0f;
#pragma unroll
        for (int d = 0; d < EMB; ++d) s += emb_s[d] * bp[d * DIM + tid];
        bias_s[tid] = s;
    }

    bf16x8 af[2][6];
#pragma unroll
    for (int mt = 0; mt < 2; ++mt)
#pragma unroll
        for (int ks = 0; ks < 6; ++ks)
            af[mt][ks] = *(const bf16x8*)&As[mt * 16 + l15][ks * 32 + quad * 8];

    f32x4 acc[2] = {};
#pragma unroll
    for (int ks = 0; ks < 6; ++ks) {
        bf16x8 bfr = *(const bf16x8*)&Ws[wave * 16 + l15][ks * 32 + quad * 8];
        acc[0] = __builtin_amdgcn_mfma_f32_16x16x32_bf16(af[0][ks], bfr, acc[0], 0, 0, 0);
        acc[1] = __builtin_amdgcn_mfma_f32_16x16x32_bf16(af[1][ks], bfr, acc[1], 0, 0, 0);
    }
    __syncthreads();

    const int o = wave * 16 + l15;
    const float bv = bias_s[o];
#pragma unroll
    for (int mt = 0; mt < 2; ++mt)
#pragma unroll
        for (int r = 0; r < 4; ++r) {
            int b = mt * 16 + quad * 4 + r;
            out[((size_t)b * N_NODES + n) * DIM + o] = acc[mt][r] + bv;
        }
}

// ---------------------------------------------------------------------------
extern "C" void kernel_launch(void* const* d_in, const int* in_sizes, int n_in,
                              void* d_out, int out_size, void* d_ws, size_t ws_size,
                              hipStream_t stream) {
    const float* x   = (const float*)d_in[0];  // [32,2000,64]
    const float* emb = (const float*)d_in[1];  // [2000,16]
    const float* nv1 = (const float*)d_in[2];  // [2000,16]
    const float* nv2 = (const float*)d_in[3];  // [16,2000]
    const float* wp  = (const float*)d_in[4];  // [16,3,64,64]
    const float* bp  = (const float*)d_in[5];  // [16,64]
    float* out = (float*)d_out;                // [32,2000,64]

    char* w = (char*)d_ws;
    bf16* Sp   = (bf16*)w;  w += (size_t)KB3 * NP * 32 * 2;           //  8.65 MB
    bf16* xTp  = (bf16*)w;  w += (size_t)BATCH * KB3 * DIM * 32 * 2;  //  8.65 MB
    bf16* y1Tp = (bf16*)w;  w += (size_t)BATCH * KB3 * DIM * 32 * 2;  //  8.65 MB
    bf16* xbf  = (bf16*)w;  w += (size_t)BATCH * N_NODES * DIM * 2;   //  8.19 MB
    bf16* y1bf = (bf16*)w;  w += (size_t)BATCH * N_NODES * DIM * 2;   //  8.19 MB
    bf16* y2bf = (bf16*)w;  w += (size_t)BATCH * N_NODES * DIM * 2;   //  8.19 MB
    bf16* wpT2 = (bf16*)w;  w += (size_t)WCOLS * 32 * 2;              //  0.79 MB
    bf16* embp = (bf16*)w;  w += (size_t)N_NODES * 32 * 2;            //  0.13 MB
    bf16* W    = (bf16*)w;                                            // 49.15 MB

    prep_fused<<<PREP_BLOCKS, 256, 0, stream>>>(
        nv1, nv2, Sp, x, xTp, xbf, wp, emb, wpT2, embp,
        Sp + (size_t)63 * NP * 32);
    // spmm1 + prep_W colocated: 512 spmm blocks + 1200 coarse prep_W blocks
    spmm_pipe4<<<512 + PW_BLOCKS, 256, 0, stream>>>(Sp, xTp, y1bf, y1Tp, embp, wpT2, W, 1);
    spmm_pipe4<<<512, 256, 0, stream>>>(Sp, y1Tp, y2bf, y1Tp, embp, wpT2, W, 0);
    combine_node<<<N_NODES, 256, 0, stream>>>(xbf, y1bf, y2bf, emb, bp, W, out);
}